// Round 14
// baseline (288.968 us; speedup 1.0000x reference)
//
#include <hip/hip_runtime.h>
#include <math.h>

// Problem constants: B=64, N=512, D=64, H=4, C=64, L=3
// Workspace layout (float-element offsets into ws, ws >= 256 MB):
//   xh   = (ushort*) ws+0        : x hi-bf16  [bn][c]  (4 MB)
//   xl   = (ushort*) ws+1048576  : x lo-bf16  [bn][c]  (4 MB)
//   hT   = ws+2097152            : h fp32 [head][c][b*512+n] (32 MB)
//   WHg  = (ushort*) ws+10485760 : W hi-bf16, 3 layers (96 KB)
//   WLg  = (ushort*) ws+10510336 : W lo-bf16 (96 KB)
//   meta = ws+10534912           : sidx,E1,E2,aZ,bZ,k (6x512KB) + s/d partials (4MB)
// R13 LESSON: wave-shfl scans fixed the LDS-port bound (295->266 us).
// R14: (a) pre-split x/W to bf16 pairs -> lin is LDS-free/barrier-free with
// direct global short8 fragment loads (kills 4x-redundant f2bf VALU);
// (b) agg_fin merges suffix+prefix passes (5 barriers/head vs 9).

using short8  = __attribute__((ext_vector_type(8))) short;
using floatx4 = __attribute__((ext_vector_type(4))) float;

__device__ inline unsigned short f2bf(float f) {
    union { float f; unsigned u; } v; v.f = f;
    unsigned u = v.u + 0x7FFFu + ((v.u >> 16) & 1u);   // round-to-nearest-even
    return (unsigned short)(u >> 16);
}
__device__ inline float bf2f(unsigned short s) {
    union { float f; unsigned u; } v; v.u = ((unsigned)s) << 16;
    return v.f;
}

// ---------------------------------------------------------------------------
// conv_split: fp32 -> bf16 hi/lo pair arrays. One float4 per thread.
// ---------------------------------------------------------------------------
__global__ __launch_bounds__(256) void conv_split(const float* __restrict__ src,
                                                  unsigned short* __restrict__ hi,
                                                  unsigned short* __restrict__ lo) {
    int idx = blockIdx.x * 256 + threadIdx.x;
    float4 v = ((const float4*)src)[idx];
    unsigned short h0 = f2bf(v.x), h1 = f2bf(v.y), h2 = f2bf(v.z), h3 = f2bf(v.w);
    ((ushort4*)hi)[idx] = make_ushort4(h0, h1, h2, h3);
    ((ushort4*)lo)[idx] = make_ushort4(f2bf(v.x - bf2f(h0)), f2bf(v.y - bf2f(h1)),
                                       f2bf(v.z - bf2f(h2)), f2bf(v.w - bf2f(h3)));
}

// ---------------------------------------------------------------------------
// Kernel A v9: MFMA split-bf16, ZERO LDS / ZERO barriers.
// Fragments loaded directly from pre-split global arrays (16-B aligned
// short8 spans). s/d dots: in-wave xor reduce, per-wave partials to global
// (prep sums 4 partials -> same grouping as R13's sred, bit-identical).
// Block = (ct head, rb row-block of 4 16-row tiles); grid 2048.
// ---------------------------------------------------------------------------
__global__ __launch_bounds__(256) void lin_kernel(const unsigned short* __restrict__ xh,
                                                  const unsigned short* __restrict__ xl,
                                                  const unsigned short* __restrict__ WHg,
                                                  const unsigned short* __restrict__ WLg,
                                                  const float* __restrict__ att_src,
                                                  const float* __restrict__ att_dst,
                                                  float* __restrict__ hT,
                                                  float* __restrict__ g_s_part,
                                                  float* __restrict__ g_d_part) {
    const int t = threadIdx.x;
    const int ct = blockIdx.x >> 9;       // head 0..3
    const int rb = blockIdx.x & 511;      // row-block (4 tiles of 16 rows)
    const int c0 = ct * 64;

    const int lane = t & 63, wv = t >> 6;
    const int mrow = lane & 15, quad = lane >> 4;
    const int c = wv * 16 + mrow;

    // B fragments: direct global loads (row = c0+c, cols kk*32+quad*8..+8)
    short8 bh[2], bl[2];
#pragma unroll
    for (int kk = 0; kk < 2; ++kk) {
        int off = (c0 + c) * 64 + kk * 32 + quad * 8;
        bh[kk] = *(const short8*)&WHg[off];
        bl[kk] = *(const short8*)&WLg[off];
    }
    const float as_c = att_src[c0 + c];
    const float ad_c = att_dst[c0 + c];

#pragma unroll 1
    for (int tt = 0; tt < 4; ++tt) {
        const int r0 = (rb * 4 + tt) * 16;

        short8 ah[2], al[2];
#pragma unroll
        for (int kk = 0; kk < 2; ++kk) {
            int off = (r0 + mrow) * 64 + kk * 32 + quad * 8;
            ah[kk] = *(const short8*)&xh[off];
            al[kk] = *(const short8*)&xl[off];
        }

        floatx4 acc = {0.f, 0.f, 0.f, 0.f};
        acc = __builtin_amdgcn_mfma_f32_16x16x32_bf16(ah[0], bh[0], acc, 0, 0, 0);
        acc = __builtin_amdgcn_mfma_f32_16x16x32_bf16(ah[1], bh[1], acc, 0, 0, 0);
        acc = __builtin_amdgcn_mfma_f32_16x16x32_bf16(ah[0], bl[0], acc, 0, 0, 0);
        acc = __builtin_amdgcn_mfma_f32_16x16x32_bf16(ah[1], bl[1], acc, 0, 0, 0);
        acc = __builtin_amdgcn_mfma_f32_16x16x32_bf16(al[0], bh[0], acc, 0, 0, 0);
        acc = __builtin_amdgcn_mfma_f32_16x16x32_bf16(al[1], bh[1], acc, 0, 0, 0);

        // Transposed store: C col=lane&15 -> channel, row=quad*4+reg -> n
        *(float4*)&hT[(size_t)(ct * 64 + c) * 32768 + r0 + quad * 4] =
            make_float4(acc[0], acc[1], acc[2], acc[3]);

        // s/d dots: reduce over the wave's 16-channel chunk (xor masks 1..8)
        float ps[4], pd[4];
#pragma unroll
        for (int reg = 0; reg < 4; ++reg) { ps[reg] = acc[reg] * as_c; pd[reg] = acc[reg] * ad_c; }
#pragma unroll
        for (int m = 1; m <= 8; m <<= 1) {
#pragma unroll
            for (int reg = 0; reg < 4; ++reg) {
                ps[reg] += __shfl_xor(ps[reg], m, 64);
                pd[reg] += __shfl_xor(pd[reg], m, 64);
            }
        }
        if (mrow == 0) {
#pragma unroll
            for (int reg = 0; reg < 4; ++reg) {
                int gn = r0 + quad * 4 + reg;
                int bh2 = (gn >> 9) * 4 + ct;
                int n  = gn & 511;
                g_s_part[((wv * 256 + bh2) << 9) + n] = ps[reg];
                g_d_part[((wv * 256 + bh2) << 9) + n] = pd[reg];
            }
        }
    }
}

// ---------------------------------------------------------------------------
// Kernel B1: attn_prep v4 — sums the 4 per-wave s/d partials (same grouping
// as R13's sred -> bit-identical). Shuffle bitonic sort + wave scans.
// ---------------------------------------------------------------------------
__global__ __launch_bounds__(256) void attn_prep(const float* __restrict__ g_s_part,
                                                 const float* __restrict__ g_d_part,
                                                 int* __restrict__ g_sidx,
                                                 float* __restrict__ g_E1,
                                                 float* __restrict__ g_E2,
                                                 float* __restrict__ g_aZ,
                                                 float* __restrict__ g_bZ,
                                                 int* __restrict__ g_k) {
    const int bh = blockIdx.x;
    const int t = threadIdx.x;
    const int lane = t & 63;
    const int wid = t >> 6;

    __shared__ float s_val[512];
    __shared__ int   s_idxE[512];
    __shared__ float z1suf[513], z2pre[513];
    __shared__ float wred[8];

    float dreg[2];
    for (int rr = 0; rr < 2; ++rr) {
        int j = t + rr * 256;
        float sv = ((g_s_part[((0 * 256 + bh) << 9) + j]  + g_s_part[((1 * 256 + bh) << 9) + j])
                  + g_s_part[((2 * 256 + bh) << 9) + j]) + g_s_part[((3 * 256 + bh) << 9) + j];
        float dv = ((g_d_part[((0 * 256 + bh) << 9) + j]  + g_d_part[((1 * 256 + bh) << 9) + j])
                  + g_d_part[((2 * 256 + bh) << 9) + j]) + g_d_part[((3 * 256 + bh) << 9) + j];
        s_val[j] = sv;
        dreg[rr] = dv;
    }
    __syncthreads();

    float v0 = s_val[2 * t], v1 = s_val[2 * t + 1];
    int id0 = 2 * t, id1 = 2 * t + 1;
    for (int k = 2; k <= 512; k <<= 1) {
        for (int j = k >> 1; j >= 1; j >>= 1) {
            bool asc = ((t & (k >> 1)) == 0);
            if (j == 1) {
                bool sw = asc ? (v0 > v1) : (v0 < v1);
                if (sw) { float tv = v0; v0 = v1; v1 = tv; int ti = id0; id0 = id1; id1 = ti; }
            } else if (j <= 64) {
                int m = j >> 1;
                float w0 = __shfl_xor(v0, m, 64);
                int  wi0 = __shfl_xor(id0, m, 64);
                float w1 = __shfl_xor(v1, m, 64);
                int  wi1 = __shfl_xor(id1, m, 64);
                bool low = ((t & m) == 0);
                bool wantmin = (low == asc);
                if (wantmin ? (w0 < v0) : (w0 > v0)) { v0 = w0; id0 = wi0; }
                if (wantmin ? (w1 < v1) : (w1 > v1)) { v1 = w1; id1 = wi1; }
            } else {
                int m = j >> 1;
                s_val[2 * t] = v0; s_val[2 * t + 1] = v1;
                s_idxE[2 * t] = id0; s_idxE[2 * t + 1] = id1;
                __syncthreads();
                int tp = t ^ m;
                float w0 = s_val[2 * tp], w1 = s_val[2 * tp + 1];
                int wi0 = s_idxE[2 * tp], wi1 = s_idxE[2 * tp + 1];
                bool low = ((t & m) == 0);
                bool wantmin = (low == asc);
                if (wantmin ? (w0 < v0) : (w0 > v0)) { v0 = w0; id0 = wi0; }
                if (wantmin ? (w1 < v1) : (w1 > v1)) { v1 = w1; id1 = wi1; }
                __syncthreads();
            }
        }
    }

    s_val[2 * t] = v0; s_val[2 * t + 1] = v1;
    __syncthreads();
    const float M = s_val[511];
    float e1_0 = __expf(v0 - M), e1_1 = __expf(v1 - M);
    float e2_0 = __expf(0.2f * (v0 - M)), e2_1 = __expf(0.2f * (v1 - M));
    *(float2*)(g_E1 + bh * 512 + 2 * t) = make_float2(e1_0, e1_1);
    *(float2*)(g_E2 + bh * 512 + 2 * t) = make_float2(e2_0, e2_1);
    *(int2*)(g_sidx + bh * 512 + 2 * t) = make_int2(id0, id1);

    float S1 = e1_0 + e1_1, S2 = e2_0 + e2_1;
    float i1 = S1, i2 = S2;
    for (int off = 1; off < 64; off <<= 1) {
        float u1 = __shfl_up(i1, off, 64);
        float u2 = __shfl_up(i2, off, 64);
        if (lane >= off) { i1 += u1; i2 += u2; }
    }
    if (lane == 63) { wred[wid] = i1; wred[4 + wid] = i2; }
    __syncthreads();
    float off1 = 0.f, off2 = 0.f;
    for (int w = 0; w < wid; ++w) { off1 += wred[w]; off2 += wred[4 + w]; }
    const float T1 = wred[0] + wred[1] + wred[2] + wred[3];
    const float T2 = wred[4] + wred[5] + wred[6] + wred[7];
    float pre1 = off1 + i1 - S1;
    float pre2 = off2 + i2 - S2;
    z1suf[2 * t] = T1 - pre1;
    z1suf[2 * t + 1] = T1 - pre1 - e1_0;
    z2pre[2 * t] = pre2;
    z2pre[2 * t + 1] = pre2 + e2_0;
    if (t == 0) { z1suf[512] = 0.f; z2pre[512] = T2; }
    __syncthreads();

    for (int rr = 0; rr < 2; ++rr) {
        int i = t + rr * 256;
        float d = dreg[rr];
        int lo = 0, hi = 512;
        while (lo < hi) {
            int mid = (lo + hi) >> 1;
            if (d + s_val[mid] >= 0.f) hi = mid; else lo = mid + 1;
        }
        int k = lo;
        float g = d + M;
        float G = (g >= 0.f) ? g : 0.2f * g;
        float al = __expf(g - G);
        float be = __expf(0.2f * g - G);
        float Z = al * z1suf[k] + be * z2pre[k];
        float inv = 1.0f / Z;
        g_aZ[bh * 512 + i] = al * inv;
        g_bZ[bh * 512 + i] = be * inv;
        g_k[bh * 512 + i]  = k;
    }
}

// ---------------------------------------------------------------------------
// Kernel B2: attn_agg_fin v5 — MERGED suffix+prefix passes (two 8.3 KB LDS
// tables coexist): 5 barriers/head vs 9, no E2 refill, no pA staging.
// Wave-owned shfl scans for segs (R13). Writes x pre-split (xh/xl) for the
// next layer's LDS-free lin. Block (b, cg 0..15); grid 1024.
// ---------------------------------------------------------------------------
#define APW 516
__global__ __launch_bounds__(256) void attn_agg_fin(const float* __restrict__ hT,
                                                    const int* __restrict__ g_sidx,
                                                    const float* __restrict__ g_E1,
                                                    const float* __restrict__ g_E2,
                                                    const float* __restrict__ g_aZ,
                                                    const float* __restrict__ g_bZ,
                                                    const int* __restrict__ g_k,
                                                    const float* __restrict__ bias,
                                                    unsigned short* __restrict__ xh,
                                                    unsigned short* __restrict__ xl) {
    const int b  = blockIdx.x & 63;
    const int cg = blockIdx.x >> 6;        // 0..15
    const int c0 = cg * 4;
    const int t = threadIdx.x;
    const int lane = t & 63, wvw = t >> 6;

    __shared__ float A1[4 * APW], A2[4 * APW];
    __shared__ float segs1[4 * 65], segs2[4 * 65];
    __shared__ float tot[4];
    __shared__ int   kA[512];
    __shared__ float aZs[512], bZs[512];

    const int cl = t & 3, ibase = t >> 2;  // cl: channel, ibase: seg 0..63
    float acc[8];
#pragma unroll
    for (int p = 0; p < 8; ++p) acc[p] = 0.f;

#pragma unroll 1
    for (int head = 0; head < 4; ++head) {
        const int bh = b * 4 + head;
        const float* hTb = hT + (size_t)(head * 64 + c0) * 32768 + b * 512;
        __syncthreads();   // prev head's queries done before table overwrite

        for (int rr = 0; rr < 2; ++rr) {
            int r = t + rr * 256;
            int j = g_sidx[bh * 512 + r];
            float e1 = g_E1[bh * 512 + r];
            float e2 = g_E2[bh * 512 + r];
            kA[r]  = g_k[bh * 512 + r];
            aZs[r] = g_aZ[bh * 512 + r];
            bZs[r] = g_bZ[bh * 512 + r];
#pragma unroll
            for (int c = 0; c < 4; ++c) {
                float hvv = hTb[c * 32768 + j];
                A1[c * APW + r] = e1 * hvv;
                A2[c * APW + r] = e2 * hvv;
            }
        }
        __syncthreads();

        // Thread-local segment sums for BOTH tables (8 rows each)
        float v1[8], v2[8];
        {
            float* b1 = A1 + cl * APW + ibase * 8;
            float* b2 = A2 + cl * APW + ibase * 8;
#pragma unroll
            for (int q4 = 0; q4 < 2; ++q4) {
                float4 a = *(const float4*)(b1 + q4 * 4);
                v1[q4 * 4] = a.x; v1[q4 * 4 + 1] = a.y; v1[q4 * 4 + 2] = a.z; v1[q4 * 4 + 3] = a.w;
                float4 c2 = *(const float4*)(b2 + q4 * 4);
                v2[q4 * 4] = c2.x; v2[q4 * 4 + 1] = c2.y; v2[q4 * 4 + 2] = c2.z; v2[q4 * 4 + 3] = c2.w;
            }
            float s1 = 0.f, s2 = 0.f;
#pragma unroll
            for (int i = 0; i < 8; ++i) { s1 += v1[i]; s2 += v2[i]; }
            segs1[cl * 65 + ibase] = s1;
            segs2[cl * 65 + ibase] = s2;
        }
        __syncthreads();
        // Wave wvw scans channel wvw's segs: suffix on segs1, prefix on segs2
        {
            float sv1 = segs1[wvw * 65 + lane];
            float suf = sv1;
#pragma unroll
            for (int off = 1; off < 64; off <<= 1) {
                float u = __shfl_down(suf, off, 64);
                if (lane + off < 64) suf += u;
            }
            segs1[wvw * 65 + lane] = suf - sv1;      // exclusive suffix
            float sv2 = segs2[wvw * 65 + lane];
            float pre = sv2;
#pragma unroll
            for (int off = 1; off < 64; off <<= 1) {
                float u = __shfl_up(pre, off, 64);
                if (lane >= off) pre += u;
            }
            segs2[wvw * 65 + lane] = pre - sv2;      // exclusive prefix
            if (lane == 63) tot[wvw] = pre;          // channel total
        }
        __syncthreads();
        // Write back scanned tables
        {
            float* b1 = A1 + cl * APW + ibase * 8;
            float* b2 = A2 + cl * APW + ibase * 8;
            float run = segs1[cl * 65 + ibase];
#pragma unroll
            for (int i = 7; i >= 0; --i) { run += v1[i]; v1[i] = run; }      // incl suffix
            float run2 = segs2[cl * 65 + ibase];
#pragma unroll
            for (int i = 0; i < 8; ++i) { float tv = v2[i]; v2[i] = run2; run2 += tv; } // excl prefix
#pragma unroll
            for (int q4 = 0; q4 < 2; ++q4) {
                *(float4*)(b1 + q4 * 4) = make_float4(v1[q4 * 4], v1[q4 * 4 + 1],
                                                      v1[q4 * 4 + 2], v1[q4 * 4 + 3]);
                *(float4*)(b2 + q4 * 4) = make_float4(v2[q4 * 4], v2[q4 * 4 + 1],
                                                      v2[q4 * 4 + 2], v2[q4 * 4 + 3]);
            }
        }
        __syncthreads();
        // Queries (both tables at once)
#pragma unroll
        for (int p = 0; p < 8; ++p) {
            int i = p * 64 + ibase;
            int k = kA[i];
            float S1 = (k < 512) ? A1[cl * APW + k] : 0.f;
            float P2 = (k < 512) ? A2[cl * APW + k] : tot[cl];
            acc[p] += aZs[i] * S1 + bZs[i] * P2;
        }
    }

    // Finalize: x = relu(mean_heads + bias), stored pre-split for next lin
    const float bv = bias[c0 + cl];
#pragma unroll
    for (int p = 0; p < 8; ++p) {
        int i = p * 64 + ibase;
        float val = fmaxf(0.25f * acc[p] + bv, 0.f);
        unsigned short h16 = f2bf(val);
        unsigned short l16 = f2bf(val - bf2f(h16));
        size_t off = (size_t)(b * 512 + i) * 64 + c0 + cl;
        xh[off] = h16;
        xl[off] = l16;
    }
}

// ---------------------------------------------------------------------------
// Kernel D: readout — reconstructs x = xh + xl (error ~|x|*2^-17, harmless).
// ---------------------------------------------------------------------------
__global__ __launch_bounds__(256) void readout_kernel(const unsigned short* __restrict__ xh,
                                                      const unsigned short* __restrict__ xl,
                                                      const float* __restrict__ rw,
                                                      const float* __restrict__ rb,
                                                      float* __restrict__ out) {
    __shared__ float red[4][64];
    __shared__ float pooled[64];
    int b = blockIdx.x, t = threadIdx.x;
    int c = t & 63, q = t >> 6;
    float acc = 0.f;
    for (int n = q; n < 512; n += 4) {
        size_t off = ((size_t)b * 512 + n) * 64 + c;
        acc += bf2f(xh[off]) + bf2f(xl[off]);
    }
    red[q][c] = acc;
    __syncthreads();
    if (t < 64) pooled[t] = (red[0][t] + red[1][t] + red[2][t] + red[3][t]) * (1.0f / 512.0f);
    __syncthreads();
    if (t < 64) {
        float a = rb[t];
        for (int cc = 0; cc < 64; ++cc) a += pooled[cc] * rw[t * 64 + cc];
        out[b * 64 + t] = a;
    }
}

extern "C" void kernel_launch(void* const* d_in, const int* in_sizes, int n_in,
                              void* d_out, int out_size, void* d_ws, size_t ws_size,
                              hipStream_t stream) {
    const float* emb       = (const float*)d_in[0];
    const float* lin_w     = (const float*)d_in[1];
    const float* att_src   = (const float*)d_in[2];
    const float* att_dst   = (const float*)d_in[3];
    const float* conv_b    = (const float*)d_in[4];
    const float* readout_w = (const float*)d_in[5];
    const float* readout_b = (const float*)d_in[6];
    float* out = (float*)d_out;

    float* ws = (float*)d_ws;
    unsigned short* xh = (unsigned short*)ws;                 // 4 MB
    unsigned short* xl = (unsigned short*)(ws + 1048576);     // 4 MB
    float* hT          = ws + 2097152;                        // 32 MB
    unsigned short* WHg = (unsigned short*)(ws + 10485760);   // 96 KB (3 layers)
    unsigned short* WLg = (unsigned short*)(ws + 10510336);   // 96 KB
    float* meta        = ws + 10534912;

    int*   g_sidx = (int*)meta;
    float* g_E1   = meta + 131072;
    float* g_E2   = meta + 262144;
    float* g_aZ   = meta + 393216;
    float* g_bZ   = meta + 524288;
    int*   g_k    = (int*)(meta + 655360);
    float* g_s_part = meta + 786432;    // [4][256][512] = 2 MB
    float* g_d_part = meta + 1310720;   // 2 MB

    // Pre-split inputs to bf16 hi/lo
    conv_split<<<2048, 256, 0, stream>>>(emb, xh, xl);         // 2M floats
    conv_split<<<48, 256, 0, stream>>>(lin_w, WHg, WLg);       // 48K floats

    for (int l = 0; l < 3; ++l) {
        lin_kernel<<<2048, 256, 0, stream>>>(xh, xl,
                                             WHg + (size_t)l * 16384, WLg + (size_t)l * 16384,
                                             att_src + l * 256, att_dst + l * 256,
                                             hT, g_s_part, g_d_part);
        attn_prep<<<256, 256, 0, stream>>>(g_s_part, g_d_part,
                                           g_sidx, g_E1, g_E2, g_aZ, g_bZ, g_k);
        attn_agg_fin<<<1024, 256, 0, stream>>>(hT, g_sidx, g_E1, g_E2, g_aZ, g_bZ, g_k,
                                               conv_b + l * 64, xh, xl);
    }
    readout_kernel<<<64, 256, 0, stream>>>(xh, xl, readout_w, readout_b, out);
}

// Round 15
// 266.143 us; speedup vs baseline: 1.0858x; 1.0858x over previous
//
#include <hip/hip_runtime.h>
#include <math.h>

// Problem constants (fixed by reference): B=64, N=512, D=64, H=4, C=64, L=3
// Workspace layout (floats), ws >= 256 MB:
//   xbuf [0 .. 2097152)         : layer activations x (8 MB)
//   hT   [2097152 .. 10485760)  : h TRANSPOSED [head][c][b*512+n] (32 MB)
//   meta [10485760 .. 11534336) : prep metadata + s/d dots (4 MB)
// R13: wave-shfl segs scans (LDS-port fix, 295->266).
// R14 LESSON: 3 changes at once (LDS-free lin, split-x 2B scattered stores,
// merged passes) regressed to 289 — reverted. R15 = R13 + ONLY the merged
// suffix+prefix agg passes (bit-identical math, 5 barriers/head vs 10).

using short8  = __attribute__((ext_vector_type(8))) short;
using floatx4 = __attribute__((ext_vector_type(4))) float;

__device__ inline unsigned short f2bf(float f) {
    union { float f; unsigned u; } v; v.f = f;
    unsigned u = v.u + 0x7FFFu + ((v.u >> 16) & 1u);   // round-to-nearest-even
    return (unsigned short)(u >> 16);
}
__device__ inline float bf2f(unsigned short s) {
    union { float f; unsigned u; } v; v.u = ((unsigned)s) << 16;
    return v.f;
}

// ---------------------------------------------------------------------------
// Kernel A v8 (MFMA split-bf16, W staged ONCE, 4 x-tiles/block). Unchanged
// from R13 (266 us best).
// ---------------------------------------------------------------------------
__global__ __launch_bounds__(256) void lin_kernel(const float* __restrict__ x,
                                                  const float* __restrict__ W,
                                                  const float* __restrict__ att_src,
                                                  const float* __restrict__ att_dst,
                                                  float* __restrict__ hT,
                                                  float* __restrict__ g_s,
                                                  float* __restrict__ g_d) {
    __shared__ unsigned short WH[64 * 72], WL[64 * 72];
    __shared__ unsigned short XH[16 * 72], XL[16 * 72];
    __shared__ float sredS[4][16], sredD[4][16];

    const int t = threadIdx.x;
    const int ct = blockIdx.x >> 9;       // head 0..3
    const int rb = blockIdx.x & 511;      // row-block (4 rt tiles)
    const int c0 = ct * 64;

#pragma unroll
    for (int q = 0; q < 4; ++q) {
        int f = q * 256 + t;
        int wrow = f >> 4, d4 = f & 15;
        float4 v = *(const float4*)(W + (size_t)(c0 + wrow) * 64 + d4 * 4);
        unsigned short h0 = f2bf(v.x), h1 = f2bf(v.y), h2 = f2bf(v.z), h3 = f2bf(v.w);
        ushort4 hi = make_ushort4(h0, h1, h2, h3);
        ushort4 lo = make_ushort4(f2bf(v.x - bf2f(h0)), f2bf(v.y - bf2f(h1)),
                                  f2bf(v.z - bf2f(h2)), f2bf(v.w - bf2f(h3)));
        *(ushort4*)&WH[wrow * 72 + d4 * 4] = hi;
        *(ushort4*)&WL[wrow * 72 + d4 * 4] = lo;
    }
    __syncthreads();

    const int lane = t & 63, wv = t >> 6;
    const int mrow = lane & 15, quad = lane >> 4;
    const int c = wv * 16 + mrow;

    short8 bh[2], bl[2];
#pragma unroll
    for (int kk = 0; kk < 2; ++kk) {
        int ko = kk * 32 + quad * 8;
        bh[kk] = *(const short8*)&WH[(wv * 16 + mrow) * 72 + ko];
        bl[kk] = *(const short8*)&WL[(wv * 16 + mrow) * 72 + ko];
    }
    const float as_c = att_src[c0 + c];
    const float ad_c = att_dst[c0 + c];

#pragma unroll 1
    for (int tt = 0; tt < 4; ++tt) {
        const int rt = rb * 4 + tt;
        const int r0 = rt * 16;
        __syncthreads();

        {
            int row = t >> 4, d4 = t & 15;
            float4 v = *(const float4*)(x + (size_t)(r0 + row) * 64 + d4 * 4);
            unsigned short h0 = f2bf(v.x), h1 = f2bf(v.y), h2 = f2bf(v.z), h3 = f2bf(v.w);
            ushort4 hi = make_ushort4(h0, h1, h2, h3);
            ushort4 lo = make_ushort4(f2bf(v.x - bf2f(h0)), f2bf(v.y - bf2f(h1)),
                                      f2bf(v.z - bf2f(h2)), f2bf(v.w - bf2f(h3)));
            *(ushort4*)&XH[row * 72 + d4 * 4] = hi;
            *(ushort4*)&XL[row * 72 + d4 * 4] = lo;
        }
        __syncthreads();

        short8 ah[2], al[2];
#pragma unroll
        for (int kk = 0; kk < 2; ++kk) {
            int ko = kk * 32 + quad * 8;
            ah[kk] = *(const short8*)&XH[mrow * 72 + ko];
            al[kk] = *(const short8*)&XL[mrow * 72 + ko];
        }

        floatx4 acc = {0.f, 0.f, 0.f, 0.f};
        acc = __builtin_amdgcn_mfma_f32_16x16x32_bf16(ah[0], bh[0], acc, 0, 0, 0);
        acc = __builtin_amdgcn_mfma_f32_16x16x32_bf16(ah[1], bh[1], acc, 0, 0, 0);
        acc = __builtin_amdgcn_mfma_f32_16x16x32_bf16(ah[0], bl[0], acc, 0, 0, 0);
        acc = __builtin_amdgcn_mfma_f32_16x16x32_bf16(ah[1], bl[1], acc, 0, 0, 0);
        acc = __builtin_amdgcn_mfma_f32_16x16x32_bf16(al[0], bh[0], acc, 0, 0, 0);
        acc = __builtin_amdgcn_mfma_f32_16x16x32_bf16(al[1], bh[1], acc, 0, 0, 0);

        *(float4*)&hT[(size_t)(ct * 64 + c) * 32768 + r0 + quad * 4] =
            make_float4(acc[0], acc[1], acc[2], acc[3]);

        float ps[4], pd[4];
#pragma unroll
        for (int reg = 0; reg < 4; ++reg) { ps[reg] = acc[reg] * as_c; pd[reg] = acc[reg] * ad_c; }
#pragma unroll
        for (int m = 1; m <= 8; m <<= 1) {
#pragma unroll
            for (int reg = 0; reg < 4; ++reg) {
                ps[reg] += __shfl_xor(ps[reg], m, 64);
                pd[reg] += __shfl_xor(pd[reg], m, 64);
            }
        }
        if (mrow < 4) {
            sredS[wv][quad * 4 + mrow] = ps[mrow];
            sredD[wv][quad * 4 + mrow] = pd[mrow];
        }
        __syncthreads();
        if (t < 16) {
            float sS = sredS[0][t] + sredS[1][t] + sredS[2][t] + sredS[3][t];
            float sD = sredD[0][t] + sredD[1][t] + sredD[2][t] + sredD[3][t];
            int gn = r0 + t;
            int bh2 = (gn >> 9) * 4 + ct;
            int n  = gn & 511;
            g_s[bh2 * 512 + n] = sS;
            g_d[bh2 * 512 + n] = sD;
        }
    }
}

// ---------------------------------------------------------------------------
// Kernel B1: attn_prep v3 — unchanged from R13.
// ---------------------------------------------------------------------------
__global__ __launch_bounds__(256) void attn_prep(const float* __restrict__ g_s,
                                                 const float* __restrict__ g_d,
                                                 int* __restrict__ g_sidx,
                                                 float* __restrict__ g_E1,
                                                 float* __restrict__ g_E2,
                                                 float* __restrict__ g_aZ,
                                                 float* __restrict__ g_bZ,
                                                 int* __restrict__ g_k) {
    const int bh = blockIdx.x;
    const int t = threadIdx.x;
    const int lane = t & 63;
    const int wid = t >> 6;

    __shared__ float s_val[512];
    __shared__ int   s_idxE[512];
    __shared__ float z1suf[513], z2pre[513];
    __shared__ float wred[8];

    float dreg[2];
    for (int rr = 0; rr < 2; ++rr) {
        int j = t + rr * 256;
        s_val[j] = g_s[bh * 512 + j];
        dreg[rr] = g_d[bh * 512 + j];
    }
    __syncthreads();

    float v0 = s_val[2 * t], v1 = s_val[2 * t + 1];
    int id0 = 2 * t, id1 = 2 * t + 1;
    for (int k = 2; k <= 512; k <<= 1) {
        for (int j = k >> 1; j >= 1; j >>= 1) {
            bool asc = ((t & (k >> 1)) == 0);
            if (j == 1) {
                bool sw = asc ? (v0 > v1) : (v0 < v1);
                if (sw) { float tv = v0; v0 = v1; v1 = tv; int ti = id0; id0 = id1; id1 = ti; }
            } else if (j <= 64) {
                int m = j >> 1;
                float w0 = __shfl_xor(v0, m, 64);
                int  wi0 = __shfl_xor(id0, m, 64);
                float w1 = __shfl_xor(v1, m, 64);
                int  wi1 = __shfl_xor(id1, m, 64);
                bool low = ((t & m) == 0);
                bool wantmin = (low == asc);
                if (wantmin ? (w0 < v0) : (w0 > v0)) { v0 = w0; id0 = wi0; }
                if (wantmin ? (w1 < v1) : (w1 > v1)) { v1 = w1; id1 = wi1; }
            } else {
                int m = j >> 1;
                s_val[2 * t] = v0; s_val[2 * t + 1] = v1;
                s_idxE[2 * t] = id0; s_idxE[2 * t + 1] = id1;
                __syncthreads();
                int tp = t ^ m;
                float w0 = s_val[2 * tp], w1 = s_val[2 * tp + 1];
                int wi0 = s_idxE[2 * tp], wi1 = s_idxE[2 * tp + 1];
                bool low = ((t & m) == 0);
                bool wantmin = (low == asc);
                if (wantmin ? (w0 < v0) : (w0 > v0)) { v0 = w0; id0 = wi0; }
                if (wantmin ? (w1 < v1) : (w1 > v1)) { v1 = w1; id1 = wi1; }
                __syncthreads();
            }
        }
    }

    s_val[2 * t] = v0; s_val[2 * t + 1] = v1;
    __syncthreads();
    const float M = s_val[511];
    float e1_0 = __expf(v0 - M), e1_1 = __expf(v1 - M);
    float e2_0 = __expf(0.2f * (v0 - M)), e2_1 = __expf(0.2f * (v1 - M));
    *(float2*)(g_E1 + bh * 512 + 2 * t) = make_float2(e1_0, e1_1);
    *(float2*)(g_E2 + bh * 512 + 2 * t) = make_float2(e2_0, e2_1);
    *(int2*)(g_sidx + bh * 512 + 2 * t) = make_int2(id0, id1);

    float S1 = e1_0 + e1_1, S2 = e2_0 + e2_1;
    float i1 = S1, i2 = S2;
    for (int off = 1; off < 64; off <<= 1) {
        float u1 = __shfl_up(i1, off, 64);
        float u2 = __shfl_up(i2, off, 64);
        if (lane >= off) { i1 += u1; i2 += u2; }
    }
    if (lane == 63) { wred[wid] = i1; wred[4 + wid] = i2; }
    __syncthreads();
    float off1 = 0.f, off2 = 0.f;
    for (int w = 0; w < wid; ++w) { off1 += wred[w]; off2 += wred[4 + w]; }
    const float T1 = wred[0] + wred[1] + wred[2] + wred[3];
    const float T2 = wred[4] + wred[5] + wred[6] + wred[7];
    float pre1 = off1 + i1 - S1;
    float pre2 = off2 + i2 - S2;
    z1suf[2 * t] = T1 - pre1;
    z1suf[2 * t + 1] = T1 - pre1 - e1_0;
    z2pre[2 * t] = pre2;
    z2pre[2 * t + 1] = pre2 + e2_0;
    if (t == 0) { z1suf[512] = 0.f; z2pre[512] = T2; }
    __syncthreads();

    for (int rr = 0; rr < 2; ++rr) {
        int i = t + rr * 256;
        float d = dreg[rr];
        int lo = 0, hi = 512;
        while (lo < hi) {
            int mid = (lo + hi) >> 1;
            if (d + s_val[mid] >= 0.f) hi = mid; else lo = mid + 1;
        }
        int k = lo;
        float g = d + M;
        float G = (g >= 0.f) ? g : 0.2f * g;
        float al = __expf(g - G);
        float be = __expf(0.2f * g - G);
        float Z = al * z1suf[k] + be * z2pre[k];
        float inv = 1.0f / Z;
        g_aZ[bh * 512 + i] = al * inv;
        g_bZ[bh * 512 + i] = be * inv;
        g_k[bh * 512 + i]  = k;
    }
}

// ---------------------------------------------------------------------------
// Kernel B2: attn_agg_fin v5' — R13 structure with MERGED suffix+prefix
// passes (two 8.3 KB tables coexist, 24.7 KB LDS total): one gather fills
// both tables, one seg-sum/scan/writeback/query sequence handles both ->
// 5 barriers/head vs ~10, no E2 refill, no pA staging. All summation orders
// bit-identical to R13. fp32 coalesced x output (R14's 2B scatter reverted).
// ---------------------------------------------------------------------------
#define APW 516
__global__ __launch_bounds__(256) void attn_agg_fin(const float* __restrict__ hT,
                                                    const int* __restrict__ g_sidx,
                                                    const float* __restrict__ g_E1,
                                                    const float* __restrict__ g_E2,
                                                    const float* __restrict__ g_aZ,
                                                    const float* __restrict__ g_bZ,
                                                    const int* __restrict__ g_k,
                                                    const float* __restrict__ bias,
                                                    float* __restrict__ x) {
    const int b  = blockIdx.x & 63;
    const int cg = blockIdx.x >> 6;        // 0..15
    const int c0 = cg * 4;
    const int t = threadIdx.x;
    const int lane = t & 63, wvw = t >> 6;

    __shared__ float A1[4 * APW], A2[4 * APW];
    __shared__ float segs1[4 * 65], segs2[4 * 65];
    __shared__ float tot[4];
    __shared__ int   kA[512];
    __shared__ float aZs[512], bZs[512];

    const int cl = t & 3, ibase = t >> 2;  // cl: channel, ibase: seg 0..63
    float acc[8];
#pragma unroll
    for (int p = 0; p < 8; ++p) acc[p] = 0.f;

#pragma unroll 1
    for (int head = 0; head < 4; ++head) {
        const int bh = b * 4 + head;
        const float* hTb = hT + (size_t)(head * 64 + c0) * 32768 + b * 512;
        __syncthreads();   // prev head's queries done before table overwrite

        // Gather: fill BOTH tables at once
        for (int rr = 0; rr < 2; ++rr) {
            int r = t + rr * 256;
            int j = g_sidx[bh * 512 + r];
            float e1 = g_E1[bh * 512 + r];
            float e2 = g_E2[bh * 512 + r];
            kA[r]  = g_k[bh * 512 + r];
            aZs[r] = g_aZ[bh * 512 + r];
            bZs[r] = g_bZ[bh * 512 + r];
#pragma unroll
            for (int c = 0; c < 4; ++c) {
                float hvv = hTb[c * 32768 + j];
                A1[c * APW + r] = e1 * hvv;
                A2[c * APW + r] = e2 * hvv;
            }
        }
        __syncthreads();

        // Thread-local segment sums for both tables (8 rows each)
        float v1[8], v2[8];
        {
            float* b1 = A1 + cl * APW + ibase * 8;
            float* b2 = A2 + cl * APW + ibase * 8;
#pragma unroll
            for (int q4 = 0; q4 < 2; ++q4) {
                float4 a = *(const float4*)(b1 + q4 * 4);
                v1[q4 * 4] = a.x; v1[q4 * 4 + 1] = a.y; v1[q4 * 4 + 2] = a.z; v1[q4 * 4 + 3] = a.w;
                float4 c2 = *(const float4*)(b2 + q4 * 4);
                v2[q4 * 4] = c2.x; v2[q4 * 4 + 1] = c2.y; v2[q4 * 4 + 2] = c2.z; v2[q4 * 4 + 3] = c2.w;
            }
            float s1 = 0.f, s2 = 0.f;
#pragma unroll
            for (int i = 0; i < 8; ++i) { s1 += v1[i]; s2 += v2[i]; }
            segs1[cl * 65 + ibase] = s1;
            segs2[cl * 65 + ibase] = s2;
        }
        __syncthreads();

        // Wave wvw scans channel wvw's segs: suffix on segs1, prefix on segs2
        {
            float sv1 = segs1[wvw * 65 + lane];
            float suf = sv1;
#pragma unroll
            for (int off = 1; off < 64; off <<= 1) {
                float u = __shfl_down(suf, off, 64);
                if (lane + off < 64) suf += u;
            }
            segs1[wvw * 65 + lane] = suf - sv1;      // exclusive suffix
            float sv2 = segs2[wvw * 65 + lane];
            float pre = sv2;
#pragma unroll
            for (int off = 1; off < 64; off <<= 1) {
                float u = __shfl_up(pre, off, 64);
                if (lane >= off) pre += u;
            }
            segs2[wvw * 65 + lane] = pre - sv2;      // exclusive prefix
            if (lane == 63) tot[wvw] = pre;          // channel total
        }
        __syncthreads();

        // Write back scanned tables (both)
        {
            float* b1 = A1 + cl * APW + ibase * 8;
            float* b2 = A2 + cl * APW + ibase * 8;
            float run = segs1[cl * 65 + ibase];
#pragma unroll
            for (int i = 7; i >= 0; --i) { run += v1[i]; v1[i] = run; }      // incl suffix
            float run2 = segs2[cl * 65 + ibase];
#pragma unroll
            for (int i = 0; i < 8; ++i) { float tv = v2[i]; v2[i] = run2; run2 += tv; } // excl prefix
#pragma unroll
            for (int q4 = 0; q4 < 2; ++q4) {
                *(float4*)(b1 + q4 * 4) = make_float4(v1[q4 * 4], v1[q4 * 4 + 1],
                                                      v1[q4 * 4 + 2], v1[q4 * 4 + 3]);
                *(float4*)(b2 + q4 * 4) = make_float4(v2[q4 * 4], v2[q4 * 4 + 1],
                                                      v2[q4 * 4 + 2], v2[q4 * 4 + 3]);
            }
        }
        __syncthreads();

        // Queries (both tables at once; same expression as R13)
#pragma unroll
        for (int p = 0; p < 8; ++p) {
            int i = p * 64 + ibase;
            int k = kA[i];
            float S1 = (k < 512) ? A1[cl * APW + k] : 0.f;
            float P2 = (k < 512) ? A2[cl * APW + k] : tot[cl];
            acc[p] += aZs[i] * S1 + bZs[i] * P2;
        }
    }

    // Finalize fused: x = relu(mean_heads + bias), fp32 coalesced
    const float bv = bias[c0 + cl];
#pragma unroll
    for (int p = 0; p < 8; ++p) {
        int i = p * 64 + ibase;
        x[(size_t)(b * 512 + i) * 64 + c0 + cl] = fmaxf(0.25f * acc[p] + bv, 0.f);
    }
}

// ---------------------------------------------------------------------------
// Kernel D: out[b][d] = (mean_n x[b][n][:]) . readout_w[d][:] + readout_b[d]
// ---------------------------------------------------------------------------
__global__ __launch_bounds__(256) void readout_kernel(const float* __restrict__ x,
                                                      const float* __restrict__ rw,
                                                      const float* __restrict__ rb,
                                                      float* __restrict__ out) {
    __shared__ float red[4][64];
    __shared__ float pooled[64];
    int b = blockIdx.x, t = threadIdx.x;
    int c = t & 63, q = t >> 6;
    float acc = 0.f;
    for (int n = q; n < 512; n += 4) acc += x[((size_t)b * 512 + n) * 64 + c];
    red[q][c] = acc;
    __syncthreads();
    if (t < 64) pooled[t] = (red[0][t] + red[1][t] + red[2][t] + red[3][t]) * (1.0f / 512.0f);
    __syncthreads();
    if (t < 64) {
        float a = rb[t];
        for (int cc = 0; cc < 64; ++cc) a += pooled[cc] * rw[t * 64 + cc];
        out[b * 64 + t] = a;
    }
}

extern "C" void kernel_launch(void* const* d_in, const int* in_sizes, int n_in,
                              void* d_out, int out_size, void* d_ws, size_t ws_size,
                              hipStream_t stream) {
    const float* emb       = (const float*)d_in[0];
    const float* lin_w     = (const float*)d_in[1];
    const float* att_src   = (const float*)d_in[2];
    const float* att_dst   = (const float*)d_in[3];
    const float* conv_b    = (const float*)d_in[4];
    const float* readout_w = (const float*)d_in[5];
    const float* readout_b = (const float*)d_in[6];
    float* out = (float*)d_out;

    float* ws   = (float*)d_ws;
    float* xbuf = ws;                    // 8 MB
    float* hT   = ws + 2097152;          // 32 MB, [head][c][b*512+n]
    float* meta = ws + 10485760;         // 4 MB

    int*   g_sidx = (int*)meta;
    float* g_E1   = meta + 131072;
    float* g_E2   = meta + 262144;
    float* g_aZ   = meta + 393216;
    float* g_bZ   = meta + 524288;
    int*   g_k    = (int*)(meta + 655360);
    float* g_s    = meta + 786432;
    float* g_d    = meta + 917504;

    for (int l = 0; l < 3; ++l) {
        const float* xin = (l == 0) ? emb : xbuf;
        lin_kernel<<<2048, 256, 0, stream>>>(xin, lin_w + (size_t)l * 16384,
                                             att_src + l * 256, att_dst + l * 256,
                                             hT, g_s, g_d);
        attn_prep<<<256, 256, 0, stream>>>(g_s, g_d,
                                           g_sidx, g_E1, g_E2, g_aZ, g_bZ, g_k);
        attn_agg_fin<<<1024, 256, 0, stream>>>(hT, g_sidx, g_E1, g_E2, g_aZ, g_bZ, g_k,
                                               conv_b + l * 64, xbuf);
    }
    readout_kernel<<<64, 256, 0, stream>>>(xbuf, readout_w, readout_b, out);
}

// Round 17
// 265.646 us; speedup vs baseline: 1.0878x; 1.0019x over previous
//
#include <hip/hip_runtime.h>
#include <math.h>

// Problem constants (fixed by reference): B=64, N=512, D=64, H=4, C=64, L=3
// Workspace layout (floats), ws >= 256 MB:
//   xbuf [0 .. 2097152)         : layer activations x (8 MB)
//   hT   [2097152 .. 10485760)  : h TRANSPOSED [head][c][b*512+n] (32 MB)
//   meta [10485760 .. 11534336) : prep metadata + s/d dots (4 MB)
// History: R13 wave-shfl segs scans (295->266). R14 (triple change) and
// R16 (cooperative mega-kernel; silent launch failure at exact-capacity
// grid) both failed -> this is the R15 known-good version (266 us).
// Remaining time budget: ~45us/iter harness d_ws re-poison (untouchable) +
// latency-bound small-kernel pipeline; traffic/occupancy/barrier knobs all
// measured-neutral (R11/R12/R15).

using short8  = __attribute__((ext_vector_type(8))) short;
using floatx4 = __attribute__((ext_vector_type(4))) float;

__device__ inline unsigned short f2bf(float f) {
    union { float f; unsigned u; } v; v.f = f;
    unsigned u = v.u + 0x7FFFu + ((v.u >> 16) & 1u);   // round-to-nearest-even
    return (unsigned short)(u >> 16);
}
__device__ inline float bf2f(unsigned short s) {
    union { float f; unsigned u; } v; v.u = ((unsigned)s) << 16;
    return v.f;
}

// ---------------------------------------------------------------------------
// Kernel A v8 (MFMA split-bf16, W staged ONCE, 4 x-tiles/block).
// ---------------------------------------------------------------------------
__global__ __launch_bounds__(256) void lin_kernel(const float* __restrict__ x,
                                                  const float* __restrict__ W,
                                                  const float* __restrict__ att_src,
                                                  const float* __restrict__ att_dst,
                                                  float* __restrict__ hT,
                                                  float* __restrict__ g_s,
                                                  float* __restrict__ g_d) {
    __shared__ unsigned short WH[64 * 72], WL[64 * 72];
    __shared__ unsigned short XH[16 * 72], XL[16 * 72];
    __shared__ float sredS[4][16], sredD[4][16];

    const int t = threadIdx.x;
    const int ct = blockIdx.x >> 9;       // head 0..3
    const int rb = blockIdx.x & 511;      // row-block (4 rt tiles)
    const int c0 = ct * 64;

#pragma unroll
    for (int q = 0; q < 4; ++q) {
        int f = q * 256 + t;
        int wrow = f >> 4, d4 = f & 15;
        float4 v = *(const float4*)(W + (size_t)(c0 + wrow) * 64 + d4 * 4);
        unsigned short h0 = f2bf(v.x), h1 = f2bf(v.y), h2 = f2bf(v.z), h3 = f2bf(v.w);
        ushort4 hi = make_ushort4(h0, h1, h2, h3);
        ushort4 lo = make_ushort4(f2bf(v.x - bf2f(h0)), f2bf(v.y - bf2f(h1)),
                                  f2bf(v.z - bf2f(h2)), f2bf(v.w - bf2f(h3)));
        *(ushort4*)&WH[wrow * 72 + d4 * 4] = hi;
        *(ushort4*)&WL[wrow * 72 + d4 * 4] = lo;
    }
    __syncthreads();

    const int lane = t & 63, wv = t >> 6;
    const int mrow = lane & 15, quad = lane >> 4;
    const int c = wv * 16 + mrow;

    short8 bh[2], bl[2];
#pragma unroll
    for (int kk = 0; kk < 2; ++kk) {
        int ko = kk * 32 + quad * 8;
        bh[kk] = *(const short8*)&WH[(wv * 16 + mrow) * 72 + ko];
        bl[kk] = *(const short8*)&WL[(wv * 16 + mrow) * 72 + ko];
    }
    const float as_c = att_src[c0 + c];
    const float ad_c = att_dst[c0 + c];

#pragma unroll 1
    for (int tt = 0; tt < 4; ++tt) {
        const int rt = rb * 4 + tt;
        const int r0 = rt * 16;
        __syncthreads();

        {
            int row = t >> 4, d4 = t & 15;
            float4 v = *(const float4*)(x + (size_t)(r0 + row) * 64 + d4 * 4);
            unsigned short h0 = f2bf(v.x), h1 = f2bf(v.y), h2 = f2bf(v.z), h3 = f2bf(v.w);
            ushort4 hi = make_ushort4(h0, h1, h2, h3);
            ushort4 lo = make_ushort4(f2bf(v.x - bf2f(h0)), f2bf(v.y - bf2f(h1)),
                                      f2bf(v.z - bf2f(h2)), f2bf(v.w - bf2f(h3)));
            *(ushort4*)&XH[row * 72 + d4 * 4] = hi;
            *(ushort4*)&XL[row * 72 + d4 * 4] = lo;
        }
        __syncthreads();

        short8 ah[2], al[2];
#pragma unroll
        for (int kk = 0; kk < 2; ++kk) {
            int ko = kk * 32 + quad * 8;
            ah[kk] = *(const short8*)&XH[mrow * 72 + ko];
            al[kk] = *(const short8*)&XL[mrow * 72 + ko];
        }

        floatx4 acc = {0.f, 0.f, 0.f, 0.f};
        acc = __builtin_amdgcn_mfma_f32_16x16x32_bf16(ah[0], bh[0], acc, 0, 0, 0);
        acc = __builtin_amdgcn_mfma_f32_16x16x32_bf16(ah[1], bh[1], acc, 0, 0, 0);
        acc = __builtin_amdgcn_mfma_f32_16x16x32_bf16(ah[0], bl[0], acc, 0, 0, 0);
        acc = __builtin_amdgcn_mfma_f32_16x16x32_bf16(ah[1], bl[1], acc, 0, 0, 0);
        acc = __builtin_amdgcn_mfma_f32_16x16x32_bf16(al[0], bh[0], acc, 0, 0, 0);
        acc = __builtin_amdgcn_mfma_f32_16x16x32_bf16(al[1], bh[1], acc, 0, 0, 0);

        *(float4*)&hT[(size_t)(ct * 64 + c) * 32768 + r0 + quad * 4] =
            make_float4(acc[0], acc[1], acc[2], acc[3]);

        float ps[4], pd[4];
#pragma unroll
        for (int reg = 0; reg < 4; ++reg) { ps[reg] = acc[reg] * as_c; pd[reg] = acc[reg] * ad_c; }
#pragma unroll
        for (int m = 1; m <= 8; m <<= 1) {
#pragma unroll
            for (int reg = 0; reg < 4; ++reg) {
                ps[reg] += __shfl_xor(ps[reg], m, 64);
                pd[reg] += __shfl_xor(pd[reg], m, 64);
            }
        }
        if (mrow < 4) {
            sredS[wv][quad * 4 + mrow] = ps[mrow];
            sredD[wv][quad * 4 + mrow] = pd[mrow];
        }
        __syncthreads();
        if (t < 16) {
            float sS = sredS[0][t] + sredS[1][t] + sredS[2][t] + sredS[3][t];
            float sD = sredD[0][t] + sredD[1][t] + sredD[2][t] + sredD[3][t];
            int gn = r0 + t;
            int bh2 = (gn >> 9) * 4 + ct;
            int n  = gn & 511;
            g_s[bh2 * 512 + n] = sS;
            g_d[bh2 * 512 + n] = sD;
        }
    }
}

// ---------------------------------------------------------------------------
// Kernel B1: attn_prep v3 — shuffle bitonic sort + wave scans.
// ---------------------------------------------------------------------------
__global__ __launch_bounds__(256) void attn_prep(const float* __restrict__ g_s,
                                                 const float* __restrict__ g_d,
                                                 int* __restrict__ g_sidx,
                                                 float* __restrict__ g_E1,
                                                 float* __restrict__ g_E2,
                                                 float* __restrict__ g_aZ,
                                                 float* __restrict__ g_bZ,
                                                 int* __restrict__ g_k) {
    const int bh = blockIdx.x;
    const int t = threadIdx.x;
    const int lane = t & 63;
    const int wid = t >> 6;

    __shared__ float s_val[512];
    __shared__ int   s_idxE[512];
    __shared__ float z1suf[513], z2pre[513];
    __shared__ float wred[8];

    float dreg[2];
    for (int rr = 0; rr < 2; ++rr) {
        int j = t + rr * 256;
        s_val[j] = g_s[bh * 512 + j];
        dreg[rr] = g_d[bh * 512 + j];
    }
    __syncthreads();

    float v0 = s_val[2 * t], v1 = s_val[2 * t + 1];
    int id0 = 2 * t, id1 = 2 * t + 1;
    for (int k = 2; k <= 512; k <<= 1) {
        for (int j = k >> 1; j >= 1; j >>= 1) {
            bool asc = ((t & (k >> 1)) == 0);
            if (j == 1) {
                bool sw = asc ? (v0 > v1) : (v0 < v1);
                if (sw) { float tv = v0; v0 = v1; v1 = tv; int ti = id0; id0 = id1; id1 = ti; }
            } else if (j <= 64) {
                int m = j >> 1;
                float w0 = __shfl_xor(v0, m, 64);
                int  wi0 = __shfl_xor(id0, m, 64);
                float w1 = __shfl_xor(v1, m, 64);
                int  wi1 = __shfl_xor(id1, m, 64);
                bool low = ((t & m) == 0);
                bool wantmin = (low == asc);
                if (wantmin ? (w0 < v0) : (w0 > v0)) { v0 = w0; id0 = wi0; }
                if (wantmin ? (w1 < v1) : (w1 > v1)) { v1 = w1; id1 = wi1; }
            } else {
                int m = j >> 1;
                s_val[2 * t] = v0; s_val[2 * t + 1] = v1;
                s_idxE[2 * t] = id0; s_idxE[2 * t + 1] = id1;
                __syncthreads();
                int tp = t ^ m;
                float w0 = s_val[2 * tp], w1 = s_val[2 * tp + 1];
                int wi0 = s_idxE[2 * tp], wi1 = s_idxE[2 * tp + 1];
                bool low = ((t & m) == 0);
                bool wantmin = (low == asc);
                if (wantmin ? (w0 < v0) : (w0 > v0)) { v0 = w0; id0 = wi0; }
                if (wantmin ? (w1 < v1) : (w1 > v1)) { v1 = w1; id1 = wi1; }
                __syncthreads();
            }
        }
    }

    s_val[2 * t] = v0; s_val[2 * t + 1] = v1;
    __syncthreads();
    const float M = s_val[511];
    float e1_0 = __expf(v0 - M), e1_1 = __expf(v1 - M);
    float e2_0 = __expf(0.2f * (v0 - M)), e2_1 = __expf(0.2f * (v1 - M));
    *(float2*)(g_E1 + bh * 512 + 2 * t) = make_float2(e1_0, e1_1);
    *(float2*)(g_E2 + bh * 512 + 2 * t) = make_float2(e2_0, e2_1);
    *(int2*)(g_sidx + bh * 512 + 2 * t) = make_int2(id0, id1);

    float S1 = e1_0 + e1_1, S2 = e2_0 + e2_1;
    float i1 = S1, i2 = S2;
    for (int off = 1; off < 64; off <<= 1) {
        float u1 = __shfl_up(i1, off, 64);
        float u2 = __shfl_up(i2, off, 64);
        if (lane >= off) { i1 += u1; i2 += u2; }
    }
    if (lane == 63) { wred[wid] = i1; wred[4 + wid] = i2; }
    __syncthreads();
    float off1 = 0.f, off2 = 0.f;
    for (int w = 0; w < wid; ++w) { off1 += wred[w]; off2 += wred[4 + w]; }
    const float T1 = wred[0] + wred[1] + wred[2] + wred[3];
    const float T2 = wred[4] + wred[5] + wred[6] + wred[7];
    float pre1 = off1 + i1 - S1;
    float pre2 = off2 + i2 - S2;
    z1suf[2 * t] = T1 - pre1;
    z1suf[2 * t + 1] = T1 - pre1 - e1_0;
    z2pre[2 * t] = pre2;
    z2pre[2 * t + 1] = pre2 + e2_0;
    if (t == 0) { z1suf[512] = 0.f; z2pre[512] = T2; }
    __syncthreads();

    for (int rr = 0; rr < 2; ++rr) {
        int i = t + rr * 256;
        float d = dreg[rr];
        int lo = 0, hi = 512;
        while (lo < hi) {
            int mid = (lo + hi) >> 1;
            if (d + s_val[mid] >= 0.f) hi = mid; else lo = mid + 1;
        }
        int k = lo;
        float g = d + M;
        float G = (g >= 0.f) ? g : 0.2f * g;
        float al = __expf(g - G);
        float be = __expf(0.2f * g - G);
        float Z = al * z1suf[k] + be * z2pre[k];
        float inv = 1.0f / Z;
        g_aZ[bh * 512 + i] = al * inv;
        g_bZ[bh * 512 + i] = be * inv;
        g_k[bh * 512 + i]  = k;
    }
}

// ---------------------------------------------------------------------------
// Kernel B2: attn_agg_fin v5' — merged suffix+prefix passes, wave-owned
// shfl segs scans, fp32 coalesced x output.
// ---------------------------------------------------------------------------
#define APW 516
__global__ __launch_bounds__(256) void attn_agg_fin(const float* __restrict__ hT,
                                                    const int* __restrict__ g_sidx,
                                                    const float* __restrict__ g_E1,
                                                    const float* __restrict__ g_E2,
                                                    const float* __restrict__ g_aZ,
                                                    const float* __restrict__ g_bZ,
                                                    const int* __restrict__ g_k,
                                                    const float* __restrict__ bias,
                                                    float* __restrict__ x) {
    const int b  = blockIdx.x & 63;
    const int cg = blockIdx.x >> 6;        // 0..15
    const int c0 = cg * 4;
    const int t = threadIdx.x;
    const int lane = t & 63, wvw = t >> 6;

    __shared__ float A1[4 * APW], A2[4 * APW];
    __shared__ float segs1[4 * 65], segs2[4 * 65];
    __shared__ float tot[4];
    __shared__ int   kA[512];
    __shared__ float aZs[512], bZs[512];

    const int cl = t & 3, ibase = t >> 2;  // cl: channel, ibase: seg 0..63
    float acc[8];
#pragma unroll
    for (int p = 0; p < 8; ++p) acc[p] = 0.f;

#pragma unroll 1
    for (int head = 0; head < 4; ++head) {
        const int bh = b * 4 + head;
        const float* hTb = hT + (size_t)(head * 64 + c0) * 32768 + b * 512;
        __syncthreads();   // prev head's queries done before table overwrite

        // Gather: fill BOTH tables at once
        for (int rr = 0; rr < 2; ++rr) {
            int r = t + rr * 256;
            int j = g_sidx[bh * 512 + r];
            float e1 = g_E1[bh * 512 + r];
            float e2 = g_E2[bh * 512 + r];
            kA[r]  = g_k[bh * 512 + r];
            aZs[r] = g_aZ[bh * 512 + r];
            bZs[r] = g_bZ[bh * 512 + r];
#pragma unroll
            for (int c = 0; c < 4; ++c) {
                float hvv = hTb[c * 32768 + j];
                A1[c * APW + r] = e1 * hvv;
                A2[c * APW + r] = e2 * hvv;
            }
        }
        __syncthreads();

        // Thread-local segment sums for both tables (8 rows each)
        float v1[8], v2[8];
        {
            float* b1 = A1 + cl * APW + ibase * 8;
            float* b2 = A2 + cl * APW + ibase * 8;
#pragma unroll
            for (int q4 = 0; q4 < 2; ++q4) {
                float4 a = *(const float4*)(b1 + q4 * 4);
                v1[q4 * 4] = a.x; v1[q4 * 4 + 1] = a.y; v1[q4 * 4 + 2] = a.z; v1[q4 * 4 + 3] = a.w;
                float4 c2 = *(const float4*)(b2 + q4 * 4);
                v2[q4 * 4] = c2.x; v2[q4 * 4 + 1] = c2.y; v2[q4 * 4 + 2] = c2.z; v2[q4 * 4 + 3] = c2.w;
            }
            float s1 = 0.f, s2 = 0.f;
#pragma unroll
            for (int i = 0; i < 8; ++i) { s1 += v1[i]; s2 += v2[i]; }
            segs1[cl * 65 + ibase] = s1;
            segs2[cl * 65 + ibase] = s2;
        }
        __syncthreads();

        // Wave wvw scans channel wvw's segs: suffix on segs1, prefix on segs2
        {
            float sv1 = segs1[wvw * 65 + lane];
            float suf = sv1;
#pragma unroll
            for (int off = 1; off < 64; off <<= 1) {
                float u = __shfl_down(suf, off, 64);
                if (lane + off < 64) suf += u;
            }
            segs1[wvw * 65 + lane] = suf - sv1;      // exclusive suffix
            float sv2 = segs2[wvw * 65 + lane];
            float pre = sv2;
#pragma unroll
            for (int off = 1; off < 64; off <<= 1) {
                float u = __shfl_up(pre, off, 64);
                if (lane >= off) pre += u;
            }
            segs2[wvw * 65 + lane] = pre - sv2;      // exclusive prefix
            if (lane == 63) tot[wvw] = pre;          // channel total
        }
        __syncthreads();

        // Write back scanned tables (both)
        {
            float* b1 = A1 + cl * APW + ibase * 8;
            float* b2 = A2 + cl * APW + ibase * 8;
            float run = segs1[cl * 65 + ibase];
#pragma unroll
            for (int i = 7; i >= 0; --i) { run += v1[i]; v1[i] = run; }      // incl suffix
            float run2 = segs2[cl * 65 + ibase];
#pragma unroll
            for (int i = 0; i < 8; ++i) { float tv = v2[i]; v2[i] = run2; run2 += tv; } // excl prefix
#pragma unroll
            for (int q4 = 0; q4 < 2; ++q4) {
                *(float4*)(b1 + q4 * 4) = make_float4(v1[q4 * 4], v1[q4 * 4 + 1],
                                                      v1[q4 * 4 + 2], v1[q4 * 4 + 3]);
                *(float4*)(b2 + q4 * 4) = make_float4(v2[q4 * 4], v2[q4 * 4 + 1],
                                                      v2[q4 * 4 + 2], v2[q4 * 4 + 3]);
            }
        }
        __syncthreads();

        // Queries (both tables at once)
#pragma unroll
        for (int p = 0; p < 8; ++p) {
            int i = p * 64 + ibase;
            int k = kA[i];
            float S1 = (k < 512) ? A1[cl * APW + k] : 0.f;
            float P2 = (k < 512) ? A2[cl * APW + k] : tot[cl];
            acc[p] += aZs[i] * S1 + bZs[i] * P2;
        }
    }

    // Finalize fused: x = relu(mean_heads + bias), fp32 coalesced
    const float bv = bias[c0 + cl];
#pragma unroll
    for (int p = 0; p < 8; ++p) {
        int i = p * 64 + ibase;
        x[(size_t)(b * 512 + i) * 64 + c0 + cl] = fmaxf(0.25f * acc[p] + bv, 0.f);
    }
}

// ---------------------------------------------------------------------------
// Kernel D: out[b][d] = (mean_n x[b][n][:]) . readout_w[d][:] + readout_b[d]
// ---------------------------------------------------------------------------
__global__ __launch_bounds__(256) void readout_kernel(const float* __restrict__ x,
                                                      const float* __restrict__ rw,
                                                      const float* __restrict__ rb,
                                                      float* __restrict__ out) {
    __shared__ float red[4][64];
    __shared__ float pooled[64];
    int b = blockIdx.x, t = threadIdx.x;
    int c = t & 63, q = t >> 6;
    float acc = 0.f;
    for (int n = q; n < 512; n += 4) acc += x[((size_t)b * 512 + n) * 64 + c];
    red[q][c] = acc;
    __syncthreads();
    if (t < 64) pooled[t] = (red[0][t] + red[1][t] + red[2][t] + red[3][t]) * (1.0f / 512.0f);
    __syncthreads();
    if (t < 64) {
        float a = rb[t];
        for (int cc = 0; cc < 64; ++cc) a += pooled[cc] * rw[t * 64 + cc];
        out[b * 64 + t] = a;
    }
}

extern "C" void kernel_launch(void* const* d_in, const int* in_sizes, int n_in,
                              void* d_out, int out_size, void* d_ws, size_t ws_size,
                              hipStream_t stream) {
    const float* emb       = (const float*)d_in[0];
    const float* lin_w     = (const float*)d_in[1];
    const float* att_src   = (const float*)d_in[2];
    const float* att_dst   = (const float*)d_in[3];
    const float* conv_b    = (const float*)d_in[4];
    const float* readout_w = (const float*)d_in[5];
    const float* readout_b = (const float*)d_in[6];
    float* out = (float*)d_out;

    float* ws   = (float*)d_ws;
    float* xbuf = ws;                    // 8 MB
    float* hT   = ws + 2097152;          // 32 MB, [head][c][b*512+n]
    float* meta = ws + 10485760;         // 4 MB

    int*   g_sidx = (int*)meta;
    float* g_E1   = meta + 131072;
    float* g_E2   = meta + 262144;
    float* g_aZ   = meta + 393216;
    float* g_bZ   = meta + 524288;
    int*   g_k    = (int*)(meta + 655360);
    float* g_s    = meta + 786432;
    float* g_d    = meta + 917504;

    for (int l = 0; l < 3; ++l) {
        const float* xin = (l == 0) ? emb : xbuf;
        lin_kernel<<<2048, 256, 0, stream>>>(xin, lin_w + (size_t)l * 16384,
                                             att_src + l * 256, att_dst + l * 256,
                                             hT, g_s, g_d);
        attn_prep<<<256, 256, 0, stream>>>(g_s, g_d,
                                           g_sidx, g_E1, g_E2, g_aZ, g_bZ, g_k);
        attn_agg_fin<<<1024, 256, 0, stream>>>(hT, g_sidx, g_E1, g_E2, g_aZ, g_bZ, g_k,
                                               conv_b + l * 64, xbuf);
    }
    readout_kernel<<<64, 256, 0, stream>>>(xbuf, readout_w, readout_b, out);
}